// Round 2
// baseline (164.914 us; speedup 1.0000x reference)
//
#include <hip/hip_runtime.h>
#include <hip/hip_bf16.h>

// Problem: B=8, A=512, IN=OUT=1024, N_OPT=16, fp32 in/out.
// out[b,a,i] = sum_j (sum_n sp[b,n] W[n,i,j]) x[b,a,j] + sum_n sp[b,n] bias[n,i]
//
// R6->R7: ATTRIBUTION PROBE. Kernels bit-identical to R6; selin_gemm is
// launched 3x (idempotent: pure function of wm/xbf/bmixed -> same out,
// same absmax). dur_us delta vs R6 = 2 x t_gemm(warm), resolving whether
// the flat 130-132us across R5/R0/R6 means (a) harness fixed cost dominates
// and gemm is ~15us (expect total ~160-180), or (b) gemm is ~50-65us and
// is the real lever (expect total ~230-260, and the gemm dispatches then
// exceed the 41us fill cutoff -> full rocprof counters become visible).

#define B_SZ 8
#define A_SZ 512
#define IN_F 1024
#define OUT_F 1024
#define N_OPT 16

typedef short short8 __attribute__((ext_vector_type(8)));
typedef float floatx4 __attribute__((ext_vector_type(4)));

__device__ __forceinline__ unsigned short f2bf(float f) {
    unsigned int u = __builtin_bit_cast(unsigned int, f);
    u += 0x7fffu + ((u >> 16) & 1u);   // RNE; inputs finite
    return (unsigned short)(u >> 16);
}

#define GLOBAL_LOAD_LDS16(g, l)                                                    \
    __builtin_amdgcn_global_load_lds(                                              \
        (const __attribute__((address_space(1))) void*)(g),                        \
        (__attribute__((address_space(3))) void*)(l), 16, 0, 0)

// ---------------------------------------------------------------------------
// Kernel 1: prep (1032 blocks).
//   blocks [0,1024):   weight mixing -> bf16 wm [8][1024][1024]  (coalesced)
//                      + x fp32->bf16 slice (4 float4/thread)
//   blocks [1024,1032): bias mixing -> fp32 bmixed [8][1024]
// ---------------------------------------------------------------------------
__global__ __launch_bounds__(256) void selin_prep(
    const float* __restrict__ x, const float* __restrict__ sp,
    const float* __restrict__ weight, const float* __restrict__ bias,
    unsigned short* __restrict__ wm, unsigned short* __restrict__ xbf,
    float* __restrict__ bmixed)
{
    const int bid = blockIdx.x;
    const int tid = threadIdx.x;

    if (bid < 1024) {
        __shared__ float sps[B_SZ * N_OPT];
        if (tid < B_SZ * N_OPT) sps[tid] = sp[tid];
        __syncthreads();
        // --- weight mixing: fully coalesced read/write streams ---
        const int e4 = bid * 256 + tid;              // float4 index into 1024x1024
        const float4* w4 = (const float4*)weight;
        float4 w[N_OPT];
#pragma unroll
        for (int n = 0; n < N_OPT; n++)
            w[n] = w4[(size_t)n * (IN_F * OUT_F / 4) + e4];
#pragma unroll
        for (int b = 0; b < B_SZ; b++) {
            float ax = 0.f, ay = 0.f, az = 0.f, aw = 0.f;
#pragma unroll
            for (int n = 0; n < N_OPT; n++) {
                float s = sps[b * N_OPT + n];
                ax += s * w[n].x; ay += s * w[n].y;
                az += s * w[n].z; aw += s * w[n].w;
            }
            ushort4 o = make_ushort4(f2bf(ax), f2bf(ay), f2bf(az), f2bf(aw));
            ((ushort4*)wm)[(size_t)b * (IN_F * OUT_F / 4) + e4] = o;
        }
        // --- x conversion slice: 1,048,576 float4 over 1024 blocks ---
#pragma unroll
        for (int j = 0; j < 4; j++) {
            const int idx = bid * 1024 + j * 256 + tid;
            float4 v = ((const float4*)x)[idx];
            ((ushort4*)xbf)[idx] =
                make_ushort4(f2bf(v.x), f2bf(v.y), f2bf(v.z), f2bf(v.w));
        }
    } else {
        __shared__ float sps[B_SZ * N_OPT];
        if (tid < B_SZ * N_OPT) sps[tid] = sp[tid];
        __syncthreads();
        const int idx = (bid - 1024) * 256 + tid;    // float4 over 8x1024
        const int b = idx >> 8, i4 = idx & 255;
        const float4* bias4 = (const float4*)bias;
        float ax = 0.f, ay = 0.f, az = 0.f, aw = 0.f;
#pragma unroll
        for (int n = 0; n < N_OPT; n++) {
            float s = sps[b * N_OPT + n];
            float4 v = bias4[n * 256 + i4];
            ax += s * v.x; ay += s * v.y; az += s * v.z; aw += s * v.w;
        }
        ((float4*)bmixed)[idx] = make_float4(ax, ay, az, aw);
    }
}

// ---------------------------------------------------------------------------
// Kernel 2: batched GEMM, C[b] = X[b] (512x1024) * Wm[b]^T (1024x1024) + bias.
// Tile 128x64, BK=64 double-buffered as 2x 32-k sub-panels (m97 bank-safe
// 64B row stride; gload_lds dest stays lane-linear). 4 waves in 2x2; each
// wave 64x32 = 4x2 frags of 16x16x32 MFMA.
// T3-minimum schedule: STAGE(next) -> COMPUTE(cur) -> __syncthreads.
// Grid: 512 blocks (2/CU, 48KB LDS); b = bid&7 XCD-L2 swizzle.
// ---------------------------------------------------------------------------
__global__ __launch_bounds__(256) void selin_gemm(
    const unsigned short* __restrict__ xbf, const unsigned short* __restrict__ wm,
    const float* __restrict__ bmixed, float* __restrict__ out)
{
    __shared__ __align__(16) unsigned short As[2][2][128 * 32];  // [dbuf][khalf] 32 KB
    __shared__ __align__(16) unsigned short Bs[2][2][64 * 32];   // [dbuf][khalf] 16 KB

    const int tid = threadIdx.x;
    const int bid = blockIdx.x;
    const int b   = bid & 7;          // XCD swizzle: same b -> same XCD
    const int tb  = bid >> 3;         // 0..63
    const int m0  = (tb & 3) * 128;   // 4 m-blocks of 128 rows
    const int n0  = (tb >> 2) * 64;   // 16 n-blocks of 64 cols

    const unsigned short* Ag = xbf + ((size_t)b * A_SZ  + m0) * IN_F;
    const unsigned short* Bg = wm  + ((size_t)b * OUT_F + n0) * IN_F;

    // 64x32 sub-panel = 4KB = 256 16B-chunks; one chunk per thread per gload.
    const int ga = (tid >> 2) * IN_F + (tid & 3) * 8;   // + k at use

    const int lane = tid & 63;
    const int wv   = tid >> 6;
    const int wmi  = wv >> 1, wni = wv & 1;   // 2x2 wave grid: 64 rows x 32 cols each
    const int lm   = lane & 15, kq = lane >> 4;

    floatx4 acc[4][2];
#pragma unroll
    for (int i = 0; i < 4; i++)
#pragma unroll
        for (int j = 0; j < 2; j++)
            acc[i][j] = (floatx4){0.f, 0.f, 0.f, 0.f};

    // 6 gloads/thread per K-step: A rows 0-63, A rows 64-127 (each khalf), B.
    auto stage = [&](int d, int kg) {
        GLOBAL_LOAD_LDS16(Ag + ga + kg,                  &As[d][0][tid * 8]);
        GLOBAL_LOAD_LDS16(Ag + ga + 64 * IN_F + kg,      &As[d][0][2048 + tid * 8]);
        GLOBAL_LOAD_LDS16(Ag + ga + kg + 32,             &As[d][1][tid * 8]);
        GLOBAL_LOAD_LDS16(Ag + ga + 64 * IN_F + kg + 32, &As[d][1][2048 + tid * 8]);
        GLOBAL_LOAD_LDS16(Bg + ga + kg,                  &Bs[d][0][tid * 8]);
        GLOBAL_LOAD_LDS16(Bg + ga + kg + 32,             &Bs[d][1][tid * 8]);
    };

    auto compute = [&](int c) {
#pragma unroll
        for (int kh = 0; kh < 2; kh++) {
            short8 a[4], bb[2];
#pragma unroll
            for (int mi = 0; mi < 4; mi++)
                a[mi] = *(const short8*)&As[c][kh][(wmi * 64 + mi * 16 + lm) * 32 + kq * 8];
#pragma unroll
            for (int ni = 0; ni < 2; ni++)
                bb[ni] = *(const short8*)&Bs[c][kh][(wni * 32 + ni * 16 + lm) * 32 + kq * 8];

#pragma unroll
            for (int mi = 0; mi < 4; mi++)
#pragma unroll
                for (int ni = 0; ni < 2; ni++)
                    acc[mi][ni] = __builtin_amdgcn_mfma_f32_16x16x32_bf16(
                        a[mi], bb[ni], acc[mi][ni], 0, 0, 0);
        }
    };

    stage(0, 0);
    __syncthreads();
    int cur = 0;
    for (int ks = 1; ks < 16; ++ks) {
        stage(cur ^ 1, ks * 64);   // issue next chunk's loads first
        compute(cur);              // ds_read+MFMA under in-flight gloads
        __syncthreads();           // vmcnt(0)+lgkmcnt(0) drain + barrier
        cur ^= 1;
    }
    compute(cur);

    // epilogue: C/D layout col=lane&15, row=(lane>>4)*4+reg (verified R5 path)
#pragma unroll
    for (int ni = 0; ni < 2; ni++) {
        const int gcol = n0 + wni * 32 + ni * 16 + lm;
        const float bv = bmixed[b * OUT_F + gcol];
#pragma unroll
        for (int mi = 0; mi < 4; mi++) {
            const int grow = m0 + wmi * 64 + mi * 16 + kq * 4;
            float* op = out + ((size_t)b * A_SZ + grow) * OUT_F + gcol;
#pragma unroll
            for (int r = 0; r < 4; r++)
                op[(size_t)r * OUT_F] = acc[mi][ni][r] + bv;
        }
    }
}

extern "C" void kernel_launch(void* const* d_in, const int* in_sizes, int n_in,
                              void* d_out, int out_size, void* d_ws, size_t ws_size,
                              hipStream_t stream) {
    const float* x      = (const float*)d_in[0];  // [8,512,1024]
    const float* sp     = (const float*)d_in[1];  // [8,16]
    const float* weight = (const float*)d_in[2];  // [16,1024,1024]
    const float* bias   = (const float*)d_in[3];  // [16,1024]
    float* out = (float*)d_out;                   // [8,512,1024]

    // workspace layout: wm bf16 16MB | xbf bf16 8MB | bmixed fp32 32KB
    unsigned short* wm  = (unsigned short*)d_ws;
    unsigned short* xbf = wm + (size_t)B_SZ * OUT_F * IN_F;
    float* bmixed       = (float*)(xbf + (size_t)B_SZ * A_SZ * IN_F);

    selin_prep<<<1032, 256, 0, stream>>>(x, sp, weight, bias, wm, xbf, bmixed);
    // ATTRIBUTION: 3x identical idempotent gemm launches.
    // dur_us - dur_us(R6) = 2 x t_gemm(warm).
    selin_gemm<<<512, 256, 0, stream>>>(xbf, wm, bmixed, out);
    selin_gemm<<<512, 256, 0, stream>>>(xbf, wm, bmixed, out);
    selin_gemm<<<512, 256, 0, stream>>>(xbf, wm, bmixed, out);
}

// Round 3
// 135.626 us; speedup vs baseline: 1.2159x; 1.2159x over previous
//
#include <hip/hip_runtime.h>
#include <hip/hip_bf16.h>

// Problem: B=8, A=512, IN=OUT=1024, N_OPT=16, fp32 in/out.
// out[b,a,i] = sum_j (sum_n sp[b,n] W[n,i,j]) x[b,a,j] + sum_n sp[b,n] bias[n,i]
//
// R7 attribution: t_gemm = 16.2us, prep ~16us, harness fixed ~100us.
// R7->R8: gemm LDS-pressure rework (the only live lever):
//   - 128x128 tile, 4 waves 2x2, wave tile 64x64 (4x4 frags of 16x16x32):
//     2.0 MFMA per ds_read_b128 (was 1.33) -> LDS-pipe cycles/FLOP halved
//   - T2 XOR swizzle via pre-swizzled GLOBAL source (rule 21: linear
//     gload_lds dest + inverse-swizzled source + swizzled read):
//     chunk stored at position g^(r&3) -> read conflict 8-way -> 4-way
//   - grid 256 (1/CU, 64KB LDS dbuf), same 2-phase stage->compute->barrier
//   - fragment C/D mapping + epilogue identical to verified path
// prep unchanged (streaming at BW floor). Single gemm launch restored.

#define B_SZ 8
#define A_SZ 512
#define IN_F 1024
#define OUT_F 1024
#define N_OPT 16

typedef short short8 __attribute__((ext_vector_type(8)));
typedef float floatx4 __attribute__((ext_vector_type(4)));

__device__ __forceinline__ unsigned short f2bf(float f) {
    unsigned int u = __builtin_bit_cast(unsigned int, f);
    u += 0x7fffu + ((u >> 16) & 1u);   // RNE; inputs finite
    return (unsigned short)(u >> 16);
}

#define GLOBAL_LOAD_LDS16(g, l)                                                    \
    __builtin_amdgcn_global_load_lds(                                              \
        (const __attribute__((address_space(1))) void*)(g),                        \
        (__attribute__((address_space(3))) void*)(l), 16, 0, 0)

// ---------------------------------------------------------------------------
// Kernel 1: prep (1032 blocks).
//   blocks [0,1024):   weight mixing -> bf16 wm [8][1024][1024]  (coalesced)
//                      + x fp32->bf16 slice (4 float4/thread)
//   blocks [1024,1032): bias mixing -> fp32 bmixed [8][1024]
// ---------------------------------------------------------------------------
__global__ __launch_bounds__(256) void selin_prep(
    const float* __restrict__ x, const float* __restrict__ sp,
    const float* __restrict__ weight, const float* __restrict__ bias,
    unsigned short* __restrict__ wm, unsigned short* __restrict__ xbf,
    float* __restrict__ bmixed)
{
    const int bid = blockIdx.x;
    const int tid = threadIdx.x;

    if (bid < 1024) {
        __shared__ float sps[B_SZ * N_OPT];
        if (tid < B_SZ * N_OPT) sps[tid] = sp[tid];
        __syncthreads();
        // --- weight mixing: fully coalesced read/write streams ---
        const int e4 = bid * 256 + tid;              // float4 index into 1024x1024
        const float4* w4 = (const float4*)weight;
        float4 w[N_OPT];
#pragma unroll
        for (int n = 0; n < N_OPT; n++)
            w[n] = w4[(size_t)n * (IN_F * OUT_F / 4) + e4];
#pragma unroll
        for (int b = 0; b < B_SZ; b++) {
            float ax = 0.f, ay = 0.f, az = 0.f, aw = 0.f;
#pragma unroll
            for (int n = 0; n < N_OPT; n++) {
                float s = sps[b * N_OPT + n];
                ax += s * w[n].x; ay += s * w[n].y;
                az += s * w[n].z; aw += s * w[n].w;
            }
            ushort4 o = make_ushort4(f2bf(ax), f2bf(ay), f2bf(az), f2bf(aw));
            ((ushort4*)wm)[(size_t)b * (IN_F * OUT_F / 4) + e4] = o;
        }
        // --- x conversion slice: 1,048,576 float4 over 1024 blocks ---
#pragma unroll
        for (int j = 0; j < 4; j++) {
            const int idx = bid * 1024 + j * 256 + tid;
            float4 v = ((const float4*)x)[idx];
            ((ushort4*)xbf)[idx] =
                make_ushort4(f2bf(v.x), f2bf(v.y), f2bf(v.z), f2bf(v.w));
        }
    } else {
        __shared__ float sps[B_SZ * N_OPT];
        if (tid < B_SZ * N_OPT) sps[tid] = sp[tid];
        __syncthreads();
        const int idx = (bid - 1024) * 256 + tid;    // float4 over 8x1024
        const int b = idx >> 8, i4 = idx & 255;
        const float4* bias4 = (const float4*)bias;
        float ax = 0.f, ay = 0.f, az = 0.f, aw = 0.f;
#pragma unroll
        for (int n = 0; n < N_OPT; n++) {
            float s = sps[b * N_OPT + n];
            float4 v = bias4[n * 256 + i4];
            ax += s * v.x; ay += s * v.y; az += s * v.z; aw += s * v.w;
        }
        ((float4*)bmixed)[idx] = make_float4(ax, ay, az, aw);
    }
}

// ---------------------------------------------------------------------------
// Kernel 2: batched GEMM, C[b] = X[b] (512x1024) * Wm[b]^T (1024x1024) + bias.
// Tile 128x128, BK=64 as two 32-k sub-panels, double-buffered (64 KB).
// Rows are 64 B in LDS (m97 bank-safe stride); within each row the four
// 16 B chunks are XOR-swizzled: global chunk g of row r lives at LDS chunk
// g^(r&3). Loader: linear LDS dest (gload_lds), source chunk (t&3)^((t>>2)&3).
// Reader: chunk kq^(lm&3). 4-way worst-case conflict (was 8-way).
// 4 waves 2x2, wave tile 64x64 = 4x4 frags of 16x16x32 MFMA.
// 2-phase: STAGE(next) -> COMPUTE(cur) -> one __syncthreads. 16 K-steps.
// Grid: 256 blocks (1/CU); b = bid&7 XCD-L2 swizzle (per-XCD set 3MB < 4MB L2).
// ---------------------------------------------------------------------------
__global__ __launch_bounds__(256) void selin_gemm(
    const unsigned short* __restrict__ xbf, const unsigned short* __restrict__ wm,
    const float* __restrict__ bmixed, float* __restrict__ out)
{
    __shared__ __align__(16) unsigned short As[2][2][128 * 32];  // [dbuf][khalf] 32 KB
    __shared__ __align__(16) unsigned short Bs[2][2][128 * 32];  // [dbuf][khalf] 32 KB

    const int tid = threadIdx.x;
    const int bid = blockIdx.x;
    const int b   = bid & 7;          // XCD swizzle: same b -> same XCD
    const int tb  = bid >> 3;         // 0..31
    const int m0  = (tb & 3) * 128;   // 4 m-blocks of 128 rows
    const int n0  = (tb >> 2) * 128;  // 8 n-blocks of 128 cols

    const unsigned short* Ag = xbf + ((size_t)b * A_SZ  + m0) * IN_F;
    const unsigned short* Bg = wm  + ((size_t)b * OUT_F + n0) * IN_F;

    // 128x32 sub-panel = 8KB = 512 16B-chunks; thread t handles chunks t and
    // t+256. Chunk c: row = c>>2, in-row position = c&3. Stored LINEARLY in
    // LDS; the GLOBAL chunk fetched is (c&3)^(row&3) (inverse swizzle), so
    // LDS position p of row r holds global chunk p^(r&3).
    const int swz = ((tid & 3) ^ ((tid >> 2) & 3)) * 8;
    const int ga0 = (tid >> 2) * IN_F + swz;             // rows 0..63   (+k at use)
    const int ga1 = ga0 + 64 * IN_F;                     // rows 64..127

    const int lane = tid & 63;
    const int wv   = tid >> 6;
    const int wmi  = wv >> 1, wni = wv & 1;   // 2x2 wave grid: 64 rows x 64 cols each
    const int lm   = lane & 15, kq = lane >> 4;
    const int rdsw = ((kq ^ (lm & 3)) - kq) * 8;  // read-side chunk XOR delta

    floatx4 acc[4][4];
#pragma unroll
    for (int i = 0; i < 4; i++)
#pragma unroll
        for (int j = 0; j < 4; j++)
            acc[i][j] = (floatx4){0.f, 0.f, 0.f, 0.f};

    // 8 gloads/thread per K-step: A(2 row-halves x 2 k-halves) + B(same).
    auto stage = [&](int d, int kg) {
        GLOBAL_LOAD_LDS16(Ag + ga0 + kg,      &As[d][0][tid * 8]);
        GLOBAL_LOAD_LDS16(Ag + ga1 + kg,      &As[d][0][2048 + tid * 8]);
        GLOBAL_LOAD_LDS16(Ag + ga0 + kg + 32, &As[d][1][tid * 8]);
        GLOBAL_LOAD_LDS16(Ag + ga1 + kg + 32, &As[d][1][2048 + tid * 8]);
        GLOBAL_LOAD_LDS16(Bg + ga0 + kg,      &Bs[d][0][tid * 8]);
        GLOBAL_LOAD_LDS16(Bg + ga1 + kg,      &Bs[d][0][2048 + tid * 8]);
        GLOBAL_LOAD_LDS16(Bg + ga0 + kg + 32, &Bs[d][1][tid * 8]);
        GLOBAL_LOAD_LDS16(Bg + ga1 + kg + 32, &Bs[d][1][2048 + tid * 8]);
    };

    auto compute = [&](int c) {
#pragma unroll
        for (int kh = 0; kh < 2; kh++) {
            short8 a[4], bb[4];
#pragma unroll
            for (int mi = 0; mi < 4; mi++)
                a[mi] = *(const short8*)
                    &As[c][kh][(wmi * 64 + mi * 16 + lm) * 32 + kq * 8 + rdsw];
#pragma unroll
            for (int ni = 0; ni < 4; ni++)
                bb[ni] = *(const short8*)
                    &Bs[c][kh][(wni * 64 + ni * 16 + lm) * 32 + kq * 8 + rdsw];
#pragma unroll
            for (int mi = 0; mi < 4; mi++)
#pragma unroll
                for (int ni = 0; ni < 4; ni++)
                    acc[mi][ni] = __builtin_amdgcn_mfma_f32_16x16x32_bf16(
                        a[mi], bb[ni], acc[mi][ni], 0, 0, 0);
        }
    };

    stage(0, 0);
    __syncthreads();
    int cur = 0;
    for (int ks = 1; ks < 16; ++ks) {
        stage(cur ^ 1, ks * 64);   // issue next chunk's loads first
        compute(cur);              // ds_read+MFMA issued under in-flight gloads
        __syncthreads();           // vmcnt(0)+lgkmcnt(0) drain + barrier
        cur ^= 1;
    }
    compute(cur);

    // epilogue: C/D layout col=lane&15, row=(lane>>4)*4+reg (verified path)
#pragma unroll
    for (int ni = 0; ni < 4; ni++) {
        const int gcol = n0 + wni * 64 + ni * 16 + lm;
        const float bv = bmixed[b * OUT_F + gcol];
#pragma unroll
        for (int mi = 0; mi < 4; mi++) {
            const int grow = m0 + wmi * 64 + mi * 16 + kq * 4;
            float* op = out + ((size_t)b * A_SZ + grow) * OUT_F + gcol;
#pragma unroll
            for (int r = 0; r < 4; r++)
                op[(size_t)r * OUT_F] = acc[mi][ni][r] + bv;
        }
    }
}

extern "C" void kernel_launch(void* const* d_in, const int* in_sizes, int n_in,
                              void* d_out, int out_size, void* d_ws, size_t ws_size,
                              hipStream_t stream) {
    const float* x      = (const float*)d_in[0];  // [8,512,1024]
    const float* sp     = (const float*)d_in[1];  // [8,16]
    const float* weight = (const float*)d_in[2];  // [16,1024,1024]
    const float* bias   = (const float*)d_in[3];  // [16,1024]
    float* out = (float*)d_out;                   // [8,512,1024]

    // workspace layout: wm bf16 16MB | xbf bf16 8MB | bmixed fp32 32KB
    unsigned short* wm  = (unsigned short*)d_ws;
    unsigned short* xbf = wm + (size_t)B_SZ * OUT_F * IN_F;
    float* bmixed       = (float*)(xbf + (size_t)B_SZ * A_SZ * IN_F);

    selin_prep<<<1032, 256, 0, stream>>>(x, sp, weight, bias, wm, xbf, bmixed);
    selin_gemm<<<256, 256, 0, stream>>>(xbf, wm, bmixed, out);
}

// Round 4
// 130.504 us; speedup vs baseline: 1.2637x; 1.0392x over previous
//
#include <hip/hip_runtime.h>
#include <hip/hip_bf16.h>

// Problem: B=8, A=512, IN=OUT=1024, N_OPT=16, fp32 in/out.
// out[b,a,i] = sum_j (sum_n sp[b,n] W[n,i,j]) x[b,a,j] + sum_n sp[b,n] bias[n,i]
//
// R8 post-mortem: 128x128@1blk/CU regressed (1 wave/SIMD, no latency hiding);
// bank-math redone: R6's 64B-row reads are already conflict-free (all 8
// 16B bank-starts, 8 lanes each). R6 gemm (16.2us) saturates NOTHING
// (MFMA 7%, LDS 32%, L2 34%, HBM 39%) -> latency-bound on the per-step
// __syncthreads vmcnt(0) drain.
//
// R8->R9: T4 counted-vmcnt dbuf on the proven R6 shape (128x64, 512 blocks,
// 2/CU, linear LDS). Loads run 2 tiles ahead (12 in flight); loop uses raw
// s_barrier + `s_waitcnt vmcnt(6)` -- never drains to 0. Schedule:
//   prologue: stage(0); stage(1); vmcnt(6); barrier
//   iter t:   compute(t); barrier; stage(t+2); vmcnt(6); barrier
//   tail:     compute(14); vmcnt(0); barrier; compute(15)
// Safety: overwrite of P[t&1] only after barrier confirming reads done;
// vmcnt(6)+barrier => ALL waves' stage(t+1) landed before anyone reads it.
// prep unchanged (streaming at BW floor).

#define B_SZ 8
#define A_SZ 512
#define IN_F 1024
#define OUT_F 1024
#define N_OPT 16

typedef short short8 __attribute__((ext_vector_type(8)));
typedef float floatx4 __attribute__((ext_vector_type(4)));

__device__ __forceinline__ unsigned short f2bf(float f) {
    unsigned int u = __builtin_bit_cast(unsigned int, f);
    u += 0x7fffu + ((u >> 16) & 1u);   // RNE; inputs finite
    return (unsigned short)(u >> 16);
}

#define GLOBAL_LOAD_LDS16(g, l)                                                    \
    __builtin_amdgcn_global_load_lds(                                              \
        (const __attribute__((address_space(1))) void*)(g),                        \
        (__attribute__((address_space(3))) void*)(l), 16, 0, 0)

// ---------------------------------------------------------------------------
// Kernel 1: prep (1032 blocks). Unchanged (streaming, ~BW floor).
// ---------------------------------------------------------------------------
__global__ __launch_bounds__(256) void selin_prep(
    const float* __restrict__ x, const float* __restrict__ sp,
    const float* __restrict__ weight, const float* __restrict__ bias,
    unsigned short* __restrict__ wm, unsigned short* __restrict__ xbf,
    float* __restrict__ bmixed)
{
    const int bid = blockIdx.x;
    const int tid = threadIdx.x;

    if (bid < 1024) {
        __shared__ float sps[B_SZ * N_OPT];
        if (tid < B_SZ * N_OPT) sps[tid] = sp[tid];
        __syncthreads();
        const int e4 = bid * 256 + tid;              // float4 index into 1024x1024
        const float4* w4 = (const float4*)weight;
        float4 w[N_OPT];
#pragma unroll
        for (int n = 0; n < N_OPT; n++)
            w[n] = w4[(size_t)n * (IN_F * OUT_F / 4) + e4];
#pragma unroll
        for (int b = 0; b < B_SZ; b++) {
            float ax = 0.f, ay = 0.f, az = 0.f, aw = 0.f;
#pragma unroll
            for (int n = 0; n < N_OPT; n++) {
                float s = sps[b * N_OPT + n];
                ax += s * w[n].x; ay += s * w[n].y;
                az += s * w[n].z; aw += s * w[n].w;
            }
            ushort4 o = make_ushort4(f2bf(ax), f2bf(ay), f2bf(az), f2bf(aw));
            ((ushort4*)wm)[(size_t)b * (IN_F * OUT_F / 4) + e4] = o;
        }
#pragma unroll
        for (int j = 0; j < 4; j++) {
            const int idx = bid * 1024 + j * 256 + tid;
            float4 v = ((const float4*)x)[idx];
            ((ushort4*)xbf)[idx] =
                make_ushort4(f2bf(v.x), f2bf(v.y), f2bf(v.z), f2bf(v.w));
        }
    } else {
        __shared__ float sps[B_SZ * N_OPT];
        if (tid < B_SZ * N_OPT) sps[tid] = sp[tid];
        __syncthreads();
        const int idx = (bid - 1024) * 256 + tid;    // float4 over 8x1024
        const int b = idx >> 8, i4 = idx & 255;
        const float4* bias4 = (const float4*)bias;
        float ax = 0.f, ay = 0.f, az = 0.f, aw = 0.f;
#pragma unroll
        for (int n = 0; n < N_OPT; n++) {
            float s = sps[b * N_OPT + n];
            float4 v = bias4[n * 256 + i4];
            ax += s * v.x; ay += s * v.y; az += s * v.z; aw += s * v.w;
        }
        ((float4*)bmixed)[idx] = make_float4(ax, ay, az, aw);
    }
}

// ---------------------------------------------------------------------------
// Kernel 2: batched GEMM, C[b] = X[b] (512x1024) * Wm[b]^T (1024x1024) + bias.
// Tile 128x64, BK=64 as two 32-k sub-panels, double-buffered (48 KB).
// 4 waves 2x2, wave tile 64x32 = 4x2 frags of 16x16x32 MFMA.
// Counted-vmcnt schedule (T4): loads 2 tiles ahead, vmcnt(6) never 0.
// Grid: 512 blocks (2/CU); b = bid&7 XCD-L2 swizzle.
// ---------------------------------------------------------------------------
__global__ __launch_bounds__(256, 2) void selin_gemm(
    const unsigned short* __restrict__ xbf, const unsigned short* __restrict__ wm,
    const float* __restrict__ bmixed, float* __restrict__ out)
{
    __shared__ __align__(16) unsigned short As[2][2][128 * 32];  // [dbuf][khalf] 32 KB
    __shared__ __align__(16) unsigned short Bs[2][2][64 * 32];   // [dbuf][khalf] 16 KB

    const int tid = threadIdx.x;
    const int bid = blockIdx.x;
    const int b   = bid & 7;          // XCD swizzle: same b -> same XCD
    const int tb  = bid >> 3;         // 0..63
    const int m0  = (tb & 3) * 128;   // 4 m-blocks of 128 rows
    const int n0  = (tb >> 2) * 64;   // 16 n-blocks of 64 cols

    const unsigned short* Ag = xbf + ((size_t)b * A_SZ  + m0) * IN_F;
    const unsigned short* Bg = wm  + ((size_t)b * OUT_F + n0) * IN_F;

    // 64x32 sub-panel = 4KB = 256 16B-chunks; one chunk per thread per gload.
    const int ga = (tid >> 2) * IN_F + (tid & 3) * 8;   // + k at use

    const int lane = tid & 63;
    const int wv   = tid >> 6;
    const int wmi  = wv >> 1, wni = wv & 1;   // 2x2 wave grid: 64 rows x 32 cols each
    const int lm   = lane & 15, kq = lane >> 4;

    floatx4 acc[4][2];
#pragma unroll
    for (int i = 0; i < 4; i++)
#pragma unroll
        for (int j = 0; j < 2; j++)
            acc[i][j] = (floatx4){0.f, 0.f, 0.f, 0.f};

    // 6 gloads/thread per tile: A rows 0-63, A rows 64-127 (each khalf), B.
    auto stage = [&](int d, int kg) {
        GLOBAL_LOAD_LDS16(Ag + ga + kg,                  &As[d][0][tid * 8]);
        GLOBAL_LOAD_LDS16(Ag + ga + 64 * IN_F + kg,      &As[d][0][2048 + tid * 8]);
        GLOBAL_LOAD_LDS16(Ag + ga + kg + 32,             &As[d][1][tid * 8]);
        GLOBAL_LOAD_LDS16(Ag + ga + 64 * IN_F + kg + 32, &As[d][1][2048 + tid * 8]);
        GLOBAL_LOAD_LDS16(Bg + ga + kg,                  &Bs[d][0][tid * 8]);
        GLOBAL_LOAD_LDS16(Bg + ga + kg + 32,             &Bs[d][1][tid * 8]);
    };

    auto compute = [&](int c) {
#pragma unroll
        for (int kh = 0; kh < 2; kh++) {
            short8 a[4], bb[2];
#pragma unroll
            for (int mi = 0; mi < 4; mi++)
                a[mi] = *(const short8*)&As[c][kh][(wmi * 64 + mi * 16 + lm) * 32 + kq * 8];
#pragma unroll
            for (int ni = 0; ni < 2; ni++)
                bb[ni] = *(const short8*)&Bs[c][kh][(wni * 32 + ni * 16 + lm) * 32 + kq * 8];
#pragma unroll
            for (int mi = 0; mi < 4; mi++)
#pragma unroll
                for (int ni = 0; ni < 2; ni++)
                    acc[mi][ni] = __builtin_amdgcn_mfma_f32_16x16x32_bf16(
                        a[mi], bb[ni], acc[mi][ni], 0, 0, 0);
        }
    };

    // --- prologue: 2 tiles in flight, wait only for tile 0 ---
    stage(0, 0);
    stage(1, 64);
    asm volatile("s_waitcnt vmcnt(6)" ::: "memory");   // my stage(0) landed
    __builtin_amdgcn_s_barrier();                      // everyone's stage(0) landed
    asm volatile("" ::: "memory");

    // --- main loop: tiles 0..13; staging runs 2 ahead (up to tile 15) ---
    for (int t = 0; t < 14; ++t) {
        const int cur = t & 1;
        compute(cur);
        __builtin_amdgcn_s_barrier();                  // all reads of P[cur] done
        asm volatile("" ::: "memory");
        stage(cur, (t + 2) * 64);                      // overwrite P[cur] with tile t+2
        asm volatile("s_waitcnt vmcnt(6)" ::: "memory"); // stage(t+1) landed (mine)
        __builtin_amdgcn_s_barrier();                  // everyone's stage(t+1) landed
        asm volatile("" ::: "memory");
    }

    // --- tail: tiles 14, 15 (stage(14),stage(15) already issued) ---
    compute(0);                                        // tile 14 (landed per last B2)
    asm volatile("s_waitcnt vmcnt(0)" ::: "memory");   // my stage(15) landed
    __builtin_amdgcn_s_barrier();                      // everyone's stage(15) landed
    asm volatile("" ::: "memory");
    compute(1);                                        // tile 15

    // epilogue: C/D layout col=lane&15, row=(lane>>4)*4+reg (verified path)
#pragma unroll
    for (int ni = 0; ni < 2; ni++) {
        const int gcol = n0 + wni * 32 + ni * 16 + lm;
        const float bv = bmixed[b * OUT_F + gcol];
#pragma unroll
        for (int mi = 0; mi < 4; mi++) {
            const int grow = m0 + wmi * 64 + mi * 16 + kq * 4;
            float* op = out + ((size_t)b * A_SZ + grow) * OUT_F + gcol;
#pragma unroll
            for (int r = 0; r < 4; r++)
                op[(size_t)r * OUT_F] = acc[mi][ni][r] + bv;
        }
    }
}

extern "C" void kernel_launch(void* const* d_in, const int* in_sizes, int n_in,
                              void* d_out, int out_size, void* d_ws, size_t ws_size,
                              hipStream_t stream) {
    const float* x      = (const float*)d_in[0];  // [8,512,1024]
    const float* sp     = (const float*)d_in[1];  // [8,16]
    const float* weight = (const float*)d_in[2];  // [16,1024,1024]
    const float* bias   = (const float*)d_in[3];  // [16,1024]
    float* out = (float*)d_out;                   // [8,512,1024]

    // workspace layout: wm bf16 16MB | xbf bf16 8MB | bmixed fp32 32KB
    unsigned short* wm  = (unsigned short*)d_ws;
    unsigned short* xbf = wm + (size_t)B_SZ * OUT_F * IN_F;
    float* bmixed       = (float*)(xbf + (size_t)B_SZ * A_SZ * IN_F);

    selin_prep<<<1032, 256, 0, stream>>>(x, sp, weight, bias, wm, xbf, bmixed);
    selin_gemm<<<512, 256, 0, stream>>>(xbf, wm, bmixed, out);
}